// Round 3
// baseline (889.702 us; speedup 1.0000x reference)
//
#include <hip/hip_runtime.h>
#include <cstdint>
#include <cstddef>

#define NCENT   100000
#define DIM     128
#define BATCH   1024
#define NCLASS  100
#define KNEIGH  200
#define GC      0.005f          // 1/(2*sigma^2), sigma=10
#define RANGE_LO (-256.0f)
#define QSCALE   64.0f          // quant steps per unit of s
#define INV_QSCALE (1.0f/64.0f)
#define ROWS_PER_TILE 32
#define CPT 2                   // centres per thread in dist kernel
#define C1_SPLIT 8
#define CAND_CAP 1024
#define E_CAP 256

// ---- replicate numpy AVX512 pairwise sum of x[k]^2, k=0..127 ----
// base case: 8 zmm accumulators (16 lanes), combine ((r0+r1)+(r2+r3))+((r4+r5)+(r6+r7)),
// then _mm512_reduce_add_ps halving tree. Contraction OFF so rounding is bit-exact.
__device__ __forceinline__ float np_sum128_sq(const float* __restrict__ x) {
#pragma clang fp contract(off)
    float v[16];
#pragma unroll
    for (int l = 0; l < 16; ++l) {
        float q0 = x[l]       * x[l];
        float q1 = x[16 + l]  * x[16 + l];
        float q2 = x[32 + l]  * x[32 + l];
        float q3 = x[48 + l]  * x[48 + l];
        float q4 = x[64 + l]  * x[64 + l];
        float q5 = x[80 + l]  * x[80 + l];
        float q6 = x[96 + l]  * x[96 + l];
        float q7 = x[112 + l] * x[112 + l];
        v[l] = ((q0 + q1) + (q2 + q3)) + ((q4 + q5) + (q6 + q7));
    }
    float t0 = v[0] + v[8],  t1 = v[1] + v[9],  t2 = v[2] + v[10], t3 = v[3] + v[11];
    float t4 = v[4] + v[12], t5 = v[5] + v[13], t6 = v[6] + v[14], t7 = v[7] + v[15];
    float u0 = t0 + t4, u1 = t1 + t5, u2 = t2 + t6, u3 = t3 + t7;
    float p0 = u0 + u2, p1 = u1 + u3;
    return p0 + p1;
}

// ---------------- norms: |x_i|^2 for rows of a [n, DIM] matrix ----------------
__global__ void norms_kernel(const float* __restrict__ x, float* __restrict__ out, int n) {
    int i = blockIdx.x * blockDim.x + threadIdx.x;
    if (i >= n) return;
    const float4* p = (const float4*)(x + (size_t)i * DIM);
    float s = 0.f;
#pragma unroll
    for (int j = 0; j < DIM / 4; ++j) {
        float4 v = p[j];
        s += v.x * v.x + v.y * v.y + v.z * v.z + v.w * v.w;
    }
    out[i] = s;
}

// ---------- dist+quant: q[r][c] = quant(cnorm[c] - 2*dot(f_r, c_c)) ----------
__global__ __launch_bounds__(256) void dist_quant_kernel(
    const float* __restrict__ feat, const float* __restrict__ cent,
    const float* __restrict__ cnorm, unsigned short* __restrict__ qmat,
    int row0) {
    __shared__ float4 fs[ROWS_PER_TILE][DIM / 4];
    const int t = threadIdx.x;
    const int rbase = row0 + blockIdx.y * ROWS_PER_TILE;

    for (int i = t; i < ROWS_PER_TILE * (DIM / 4); i += 256) {
        int r = i >> 5, j = i & 31;
        fs[r][j] = ((const float4*)(feat + (size_t)(rbase + r) * DIM))[j];
    }
    __syncthreads();

    const int c0 = blockIdx.x * (256 * CPT) + t;
    if (c0 >= NCENT) return;               // no further barriers below
    const int c1 = c0 + 256;
    const bool v1 = (c1 < NCENT);

    const float4* cp0 = (const float4*)(cent + (size_t)c0 * DIM);
    const float4* cp1 = (const float4*)(cent + (size_t)(v1 ? c1 : c0) * DIM);

    float acc0[ROWS_PER_TILE], acc1[ROWS_PER_TILE];
#pragma unroll
    for (int r = 0; r < ROWS_PER_TILE; ++r) { acc0[r] = 0.f; acc1[r] = 0.f; }

#pragma unroll 2
    for (int j = 0; j < DIM / 4; ++j) {
        float4 a = cp0[j];
        float4 b = cp1[j];
#pragma unroll
        for (int r = 0; r < ROWS_PER_TILE; ++r) {
            float4 f4 = fs[r][j];
            acc0[r] = fmaf(a.x, f4.x, fmaf(a.y, f4.y, fmaf(a.z, f4.z, fmaf(a.w, f4.w, acc0[r]))));
            acc1[r] = fmaf(b.x, f4.x, fmaf(b.y, f4.y, fmaf(b.z, f4.z, fmaf(b.w, f4.w, acc1[r]))));
        }
    }

    const float cn0 = cnorm[c0];
    const float cn1 = v1 ? cnorm[c1] : 0.f;
    const int lrow0 = blockIdx.y * ROWS_PER_TILE;
#pragma unroll
    for (int r = 0; r < ROWS_PER_TILE; ++r) {
        float s0 = cn0 - 2.0f * acc0[r];
        int q0 = (int)floorf((s0 - RANGE_LO) * QSCALE);
        q0 = q0 < 0 ? 0 : (q0 > 65535 ? 65535 : q0);
        qmat[(size_t)(lrow0 + r) * NCENT + c0] = (unsigned short)q0;
        if (v1) {
            float s1 = cn1 - 2.0f * acc1[r];
            int q1 = (int)floorf((s1 - RANGE_LO) * QSCALE);
            q1 = q1 < 0 ? 0 : (q1 > 65535 ? 65535 : q1);
            qmat[(size_t)(lrow0 + r) * NCENT + c1] = (unsigned short)q1;
        }
    }
}

// -------- hist: per-row 4096-bin coarse histogram of (q >> 4), split blocks --------
__global__ __launch_bounds__(256) void hist_kernel(
    const unsigned short* __restrict__ qmat, unsigned int* __restrict__ rowhist) {
    __shared__ unsigned int h[4096];
    const int t = threadIdx.x;
    for (int i = t; i < 4096; i += 256) h[i] = 0;
    __syncthreads();

    const int lr = blockIdx.x;
    const int part = blockIdx.y;
    const int chunk = NCENT / C1_SPLIT;      // 12500 (even)
    const uint32_t* p = (const uint32_t*)(qmat + (size_t)lr * NCENT + (size_t)part * chunk);
    const int n32 = chunk / 2;               // 6250
    for (int i = t; i < n32; i += 256) {
        uint32_t v = p[i];
        atomicAdd(&h[(v & 0xffffu) >> 4], 1u);
        atomicAdd(&h[(v >> 16) >> 4], 1u);
    }
    __syncthreads();

    unsigned int* gh = rowhist + (size_t)lr * 4096;
    for (int i = t; i < 4096; i += 256)
        if (h[i]) atomicAdd(&gh[i], h[i]);
}

// -------- select + class-accumulate + normalize, one block per row --------
// Boundary resolution replicates the np float32 reference bit-for-bit:
//   key32 = (fn32 - B) + cn32, B = sequential k-ascending fmaf chain of (2f_k)*c_k
//   (OpenBLAS sgemm micro-kernel rounding), fn32/cn32 = numpy AVX512 pairwise sums.
// Items >= 2 fine-quanta away from the cut are decided by quantized counts
// (margin ~0.016 >> total fp32 noise ~2e-3); the +-2-quantum window is ranked
// by replicated key32 with index tie-break (stable top_k semantics).
__global__ __launch_bounds__(256) void select_kernel(
    const unsigned short* __restrict__ qmat, const unsigned int* __restrict__ rowhist,
    const float* __restrict__ feat, const float* __restrict__ cent,
    const float* __restrict__ cnorm, const float* __restrict__ fnorm,
    const float* __restrict__ kw, const int* __restrict__ labels,
    float* __restrict__ out, int row0) {

    __shared__ unsigned int h[4096];
    __shared__ unsigned int part_s[256];
    __shared__ float p[NCLASS];
    __shared__ int candIdx[CAND_CAP];
    __shared__ unsigned short candQ[CAND_CAP];
    __shared__ int ncand;
    __shared__ int bcut_s, below2_s;
    __shared__ unsigned int hf[48];
    __shared__ int qcutFrel_s, needE_s;
    __shared__ float fnrep_s;
    __shared__ int eIdx[E_CAP];
    __shared__ float eKey[E_CAP];
    __shared__ float eW[E_CAP];
    __shared__ int nE;
    __shared__ float ssum;

    const int t = threadIdx.x;
    const int lr = blockIdx.x;
    const int grow = row0 + lr;

    for (int i = t; i < 4096; i += 256) h[i] = rowhist[(size_t)lr * 4096 + i];
    for (int i = t; i < NCLASS; i += 256) p[i] = 0.f;
    for (int i = t; i < 48; i += 256) hf[i] = 0;
    if (t == 0) { ncand = 0; nE = 0; }
    __syncthreads();

    // coarse cut bin: count(b < bcut) < K <= count(b <= bcut)
    unsigned int ps = 0;
#pragma unroll
    for (int j = 0; j < 16; ++j) ps += h[t * 16 + j];
    part_s[t] = ps;
    __syncthreads();
    if (t == 0) {
        unsigned int cum = 0; int seg = 255;
        for (int i = 0; i < 256; ++i) {
            if (cum + part_s[i] >= KNEIGH) { seg = i; break; }
            cum += part_s[i];
        }
        int bcut = seg * 16 + 15;
        for (int b = seg * 16; b < seg * 16 + 16; ++b) {
            if (cum + h[b] >= KNEIGH) { bcut = b; break; }
            cum += h[b];
        }
        bcut_s = bcut;
        int below = (int)cum;                                   // count b < bcut
        below2_s = below - (bcut >= 1 ? (int)h[bcut - 1] : 0);  // count b <= bcut-2
    }
    __syncthreads();
    const int bcut = bcut_s;
    const int blo = bcut > 0 ? bcut - 1 : 0;
    const int bhi = bcut < 4095 ? bcut + 1 : 4095;
    const int below2 = below2_s;
    const float fn = fnorm[grow];

    // row pass: definite members (b < blo) accumulate; b in [blo,bhi] -> candidates
    const uint32_t* qp = (const uint32_t*)(qmat + (size_t)lr * NCENT);
    for (int i = t; i < NCENT / 2; i += 256) {
        uint32_t v = qp[i];
#pragma unroll
        for (int half = 0; half < 2; ++half) {
            unsigned int q = half ? (v >> 16) : (v & 0xffffu);
            int b = (int)(q >> 4);
            if (b < blo) {
                int idx = 2 * i + half;
                float smid = RANGE_LO + ((float)q + 0.5f) * INV_QSCALE;
                float w = expf(kw[idx] - (fn + smid) * GC);
                atomicAdd(&p[labels[idx]], w);
            } else if (b <= bhi) {
                int idx = 2 * i + half;
                int pos = atomicAdd(&ncand, 1);
                if (pos < CAND_CAP) { candIdx[pos] = idx; candQ[pos] = (unsigned short)q; }
                atomicAdd(&hf[(int)q - blo * 16], 1u);
            }
        }
    }
    __syncthreads();
    const int nc = ncand < CAND_CAP ? ncand : CAND_CAP;

    // fine cut quantum among candidates
    if (t == 0) {
        int need = KNEIGH - below2;
        int nb = (bhi - blo + 1) * 16;
        int cum = 0, qc = nb - 1;
        for (int rq = 0; rq < nb; ++rq) {
            if (cum + (int)hf[rq] >= need) { qc = rq; break; }
            cum += (int)hf[rq];
        }
        int cumM3 = 0;
        for (int rq = 0; rq <= qc - 3; ++rq) cumM3 += (int)hf[rq];
        qcutFrel_s = qc;
        needE_s = need - cumM3;   // how many to take from the 5-quantum window
        fnrep_s = np_sum128_sq(feat + (size_t)grow * DIM);
    }
    __syncthreads();
    const int qc = qcutFrel_s;
    const int needE = needE_s;
    const float fnrep = fnrep_s;

    // definite candidates (rq <= qc-3) accumulate; window [qc-2, qc+2] -> E
    for (int i = t; i < nc; i += 256) {
        int rq = (int)candQ[i] - blo * 16;
        if (rq <= qc - 3) {
            int idx = candIdx[i];
            unsigned int q = candQ[i];
            float smid = RANGE_LO + ((float)q + 0.5f) * INV_QSCALE;
            float w = expf(kw[idx] - (fn + smid) * GC);
            atomicAdd(&p[labels[idx]], w);
        } else if (rq <= qc + 2) {
            int pos = atomicAdd(&nE, 1);
            if (pos < E_CAP) eIdx[pos] = candIdx[i];
        }
    }
    __syncthreads();
    const int ne = nE < E_CAP ? nE : E_CAP;

    // replicated np-fp32 keys for the ambiguous window (+ fp64 distance for weights)
    const float* fp = feat + (size_t)grow * DIM;
    for (int i = t; i < ne; i += 256) {
        int idx = eIdx[i];
        const float* cp = cent + (size_t)idx * DIM;
        // sgemm chain: single accumulator, k ascending, fma of (2*f_k)*c_k
        float acc = 0.f;
#pragma unroll
        for (int k = 0; k < DIM; ++k) acc = fmaf(2.0f * fp[k], cp[k], acc);
        float cnrep = np_sum128_sq(cp);
        {
#pragma clang fp contract(off)
            eKey[i] = (fnrep - acc) + cnrep;
        }
        double dd = 0.0;
        for (int k = 0; k < DIM; ++k) {
            double d1 = (double)fp[k] - (double)cp[k];
            dd += d1 * d1;
        }
        eW[i] = (float)dd;
    }
    __syncthreads();

    // rank by replicated key, index tie-break (stable top_k); take needE smallest
    for (int i = t; i < ne; i += 256) {
        float ki = eKey[i]; int ii = eIdx[i]; int rank = 0;
        for (int j = 0; j < ne; ++j) {
            if (j == i) continue;
            float kj = eKey[j];
            if (kj < ki || (kj == ki && eIdx[j] < ii)) rank++;
        }
        if (rank < needE) {
            float w = expf(kw[ii] - eW[i] * GC);
            atomicAdd(&p[labels[ii]], w);
        }
    }
    __syncthreads();

    // normalize: p = where(p==0, 1e-10, p); p /= sum(p); out = log(p)
    if (t == 0) {
        float s = 0.f;
        for (int c = 0; c < NCLASS; ++c) {
            float v = p[c];
            v = (v == 0.f) ? 1e-10f : v;
            p[c] = v;
            s += v;
        }
        ssum = s;
    }
    __syncthreads();
    for (int c = t; c < NCLASS; c += 256)
        out[(size_t)grow * NCLASS + c] = logf(p[c] / ssum);
}

static inline size_t align256(size_t x) { return (x + 255) & ~(size_t)255; }

extern "C" void kernel_launch(void* const* d_in, const int* in_sizes, int n_in,
                              void* d_out, int out_size, void* d_ws, size_t ws_size,
                              hipStream_t stream) {
    const float* feat   = (const float*)d_in[0];  // [1024,128]
    const float* cent   = (const float*)d_in[1];  // [100000,128]
    const float* kw     = (const float*)d_in[2];  // [100000]
    const int*   labels = (const int*)d_in[3];    // [100000]
    float* out = (float*)d_out;                   // [1024,100]

    // choose rows per group based on available workspace
    int R = 1024;
    while (R > 32) {
        size_t need = align256((size_t)R * NCENT * 2)       // qmat u16
                    + align256((size_t)R * 4096 * 4)        // rowhist u32
                    + align256((size_t)NCENT * 4)           // cnorm
                    + align256((size_t)BATCH * 4);          // fnorm
        if (need <= ws_size) break;
        R >>= 1;
    }

    char* base = (char*)d_ws;
    size_t o = 0;
    unsigned short* qmat = (unsigned short*)(base + o); o += align256((size_t)R * NCENT * 2);
    unsigned int* rowhist = (unsigned int*)(base + o);  o += align256((size_t)R * 4096 * 4);
    float* cnorm = (float*)(base + o);                  o += align256((size_t)NCENT * 4);
    float* fnorm = (float*)(base + o);

    norms_kernel<<<(NCENT + 255) / 256, 256, 0, stream>>>(cent, cnorm, NCENT);
    norms_kernel<<<(BATCH + 255) / 256, 256, 0, stream>>>(feat, fnorm, BATCH);

    const int ngroups = BATCH / R;
    const int cblocks = (NCENT + 256 * CPT - 1) / (256 * CPT);
    for (int g = 0; g < ngroups; ++g) {
        int row0 = g * R;
        hipMemsetAsync(rowhist, 0, (size_t)R * 4096 * 4, stream);
        dim3 gb(cblocks, R / ROWS_PER_TILE);
        dist_quant_kernel<<<gb, 256, 0, stream>>>(feat, cent, cnorm, qmat, row0);
        dim3 gh(R, C1_SPLIT);
        hist_kernel<<<gh, 256, 0, stream>>>(qmat, rowhist);
        select_kernel<<<R, 256, 0, stream>>>(qmat, rowhist, feat, cent, cnorm, fnorm,
                                             kw, labels, out, row0);
    }
}

// Round 4
// 688.059 us; speedup vs baseline: 1.2931x; 1.2931x over previous
//
#include <hip/hip_runtime.h>
#include <cstdint>
#include <cstddef>

#define NCENT   100000
#define DIM     128
#define BATCH   1024
#define NCLASS  100
#define KNEIGH  200
#define GC      0.005f          // 1/(2*sigma^2), sigma=10
#define HIST_MAX 160            // only histogram bins < 160 (s < 96); cut ~ bin 113
#define MARGIN   8              // candidate window: bin <= cutbin + 8 (covers 2*eps+1, eps<=2)
#define CAND_CAP 2048

typedef __attribute__((ext_vector_type(8))) short s8v;   // 8 bf16
typedef __attribute__((ext_vector_type(4))) float f4v;   // 4 f32 acc

static __device__ __forceinline__ unsigned short f2bf(float x) {
    uint32_t b = __float_as_uint(x);
    uint32_t r = (b + 0x7fffu + ((b >> 16) & 1u)) >> 16;   // RNE
    return (unsigned short)r;
}

// ---- replicate numpy AVX512 pairwise sum of x[k]^2, k=0..127 (round-3 verified) ----
__device__ __forceinline__ float np_sum128_sq(const float* __restrict__ x) {
#pragma clang fp contract(off)
    float v[16];
#pragma unroll
    for (int l = 0; l < 16; ++l) {
        float q0 = x[l]       * x[l];
        float q1 = x[16 + l]  * x[16 + l];
        float q2 = x[32 + l]  * x[32 + l];
        float q3 = x[48 + l]  * x[48 + l];
        float q4 = x[64 + l]  * x[64 + l];
        float q5 = x[80 + l]  * x[80 + l];
        float q6 = x[96 + l]  * x[96 + l];
        float q7 = x[112 + l] * x[112 + l];
        v[l] = ((q0 + q1) + (q2 + q3)) + ((q4 + q5) + (q6 + q7));
    }
    float t0 = v[0] + v[8],  t1 = v[1] + v[9],  t2 = v[2] + v[10], t3 = v[3] + v[11];
    float t4 = v[4] + v[12], t5 = v[5] + v[13], t6 = v[6] + v[14], t7 = v[7] + v[15];
    float u0 = t0 + t4, u1 = t1 + t5, u2 = t2 + t6, u3 = t3 + t7;
    float p0 = u0 + u2, p1 = u1 + u3;
    return p0 + p1;
}

// ---- prep: centres f32 -> bf16 + fp32 norms. 8 threads/centre, 32 centres/block ----
__global__ __launch_bounds__(256) void prep_cent_kernel(
    const float* __restrict__ cent, unsigned short* __restrict__ centb,
    float* __restrict__ cnorm) {
    const int t = threadIdx.x;
    const int c = blockIdx.x * 32 + (t >> 3);   // grid 3125 * 32 = 100000 exact
    const int p = t & 7;
    const float4* src = (const float4*)(cent + (size_t)c * DIM + p * 16);
    float s = 0.f;
    unsigned short tmp[16];
#pragma unroll
    for (int j = 0; j < 4; ++j) {
        float4 v = src[j];
        s += v.x * v.x + v.y * v.y + v.z * v.z + v.w * v.w;
        tmp[4 * j + 0] = f2bf(v.x); tmp[4 * j + 1] = f2bf(v.y);
        tmp[4 * j + 2] = f2bf(v.z); tmp[4 * j + 3] = f2bf(v.w);
    }
    s += __shfl_xor(s, 1); s += __shfl_xor(s, 2); s += __shfl_xor(s, 4);
    if (p == 0) cnorm[c] = s;
    uint4 o0, o1;
    o0.x = (uint32_t)tmp[0]  | ((uint32_t)tmp[1]  << 16);
    o0.y = (uint32_t)tmp[2]  | ((uint32_t)tmp[3]  << 16);
    o0.z = (uint32_t)tmp[4]  | ((uint32_t)tmp[5]  << 16);
    o0.w = (uint32_t)tmp[6]  | ((uint32_t)tmp[7]  << 16);
    o1.x = (uint32_t)tmp[8]  | ((uint32_t)tmp[9]  << 16);
    o1.y = (uint32_t)tmp[10] | ((uint32_t)tmp[11] << 16);
    o1.z = (uint32_t)tmp[12] | ((uint32_t)tmp[13] << 16);
    o1.w = (uint32_t)tmp[14] | ((uint32_t)tmp[15] << 16);
    uint4* dst = (uint4*)(centb + (size_t)c * DIM + p * 16);
    dst[0] = o0; dst[1] = o1;
}

// ---- prep: feat f32 -> bf16 + np-replicated |f|^2 per row ----
__global__ __launch_bounds__(256) void prep_feat_kernel(
    const float* __restrict__ feat, unsigned short* __restrict__ featb,
    float* __restrict__ fnrep) {
    const int r = blockIdx.x * 256 + threadIdx.x;
    if (r >= BATCH) return;
    const float* fp = feat + (size_t)r * DIM;
    fnrep[r] = np_sum128_sq(fp);
    unsigned short* dst = featb + (size_t)r * DIM;
    for (int k = 0; k < DIM; ++k) dst[k] = f2bf(fp[k]);
}

// ---- coarse distance via bf16 MFMA: qmat[row][col] = clamp(floor(cn - 2*dot) + 64) ----
// block: 4 waves, 128 rows x 64 cols per iteration, 8 iterations (512 cols/block)
__global__ __launch_bounds__(256, 2) void mfma_coarse_kernel(
    const unsigned short* __restrict__ featb, const unsigned short* __restrict__ centb,
    const float* __restrict__ cnorm, unsigned char* __restrict__ qmat) {
    const int w = threadIdx.x >> 6;
    const int lane = threadIdx.x & 63;
    const int lrow = lane & 15;
    const int lk = (lane >> 4) * 8;
    const int row0 = blockIdx.y * 128;
    const int colbase = blockIdx.x * 512;

    // A fragments: rows row0 + rs*16 + (lane&15), k = ks*32 + (lane>>4)*8 + j
    s8v a[8][4];
#pragma unroll
    for (int rs = 0; rs < 8; ++rs)
#pragma unroll
        for (int ks = 0; ks < 4; ++ks)
            a[rs][ks] = *(const s8v*)(featb + (size_t)(row0 + rs * 16 + lrow) * DIM + ks * 32 + lk);

    for (int it = 0; it < 8; ++it) {
        const int c0 = colbase + it * 64 + w * 16;
        const int ccol = c0 + lrow;                 // this lane's B column / D column
        const int cc = ccol < NCENT ? ccol : NCENT - 1;
        const bool valid = (ccol < NCENT);

        f4v acc[8];
#pragma unroll
        for (int rs = 0; rs < 8; ++rs) acc[rs] = (f4v){0.f, 0.f, 0.f, 0.f};

#pragma unroll
        for (int ks = 0; ks < 4; ++ks) {
            s8v b = *(const s8v*)(centb + (size_t)cc * DIM + ks * 32 + lk);
#pragma unroll
            for (int rs = 0; rs < 8; ++rs)
                acc[rs] = __builtin_amdgcn_mfma_f32_16x16x32_bf16(a[rs][ks], b, acc[rs], 0, 0, 0);
        }

        const float cn = cnorm[cc];
        if (valid) {
#pragma unroll
            for (int rs = 0; rs < 8; ++rs) {
#pragma unroll
                for (int j = 0; j < 4; ++j) {
                    float s = cn - 2.0f * acc[rs][j];
                    int bin = (int)floorf(s) + 64;
                    bin = bin < 0 ? 0 : (bin > 255 ? 255 : bin);
                    int row = row0 + rs * 16 + (lane >> 4) * 4 + j;
                    qmat[(size_t)row * NCENT + ccol] = (unsigned char)bin;
                }
            }
        }
    }
}

// ---- select: hist -> cut -> gather candidates -> exact np-fp32 keys -> top-200 ----
__global__ __launch_bounds__(256) void select_kernel(
    const unsigned char* __restrict__ qmat,
    const float* __restrict__ feat, const float* __restrict__ cent,
    const float* __restrict__ fnrep,
    const float* __restrict__ kw, const int* __restrict__ labels,
    float* __restrict__ out) {

    __shared__ unsigned int hist[256];
    __shared__ int candIdx[CAND_CAP];
    __shared__ float candKey[CAND_CAP];
    __shared__ float candW[CAND_CAP];
    __shared__ float p[NCLASS];
    __shared__ int ncand;
    __shared__ int thr_s;
    __shared__ float ssum;

    const int t = threadIdx.x;
    const int row = blockIdx.x;
    const uint32_t* qp = (const uint32_t*)(qmat + (size_t)row * NCENT); // row stride 100000 % 16 == 0

    for (int i = t; i < 256; i += 256) hist[i] = 0;
    for (int i = t; i < NCLASS; i += 256) p[i] = 0.f;
    if (t == 0) ncand = 0;
    __syncthreads();

    // pass 1: coarse histogram of the low tail
    for (int i = t; i < NCENT / 4; i += 256) {
        uint32_t v = qp[i];
        unsigned b0 = v & 255u, b1 = (v >> 8) & 255u, b2 = (v >> 16) & 255u, b3 = v >> 24;
        if (b0 < HIST_MAX) atomicAdd(&hist[b0], 1u);
        if (b1 < HIST_MAX) atomicAdd(&hist[b1], 1u);
        if (b2 < HIST_MAX) atomicAdd(&hist[b2], 1u);
        if (b3 < HIST_MAX) atomicAdd(&hist[b3], 1u);
    }
    __syncthreads();
    if (t == 0) {
        unsigned int cum = 0; int cutbin = HIST_MAX - 1;
        for (int b = 0; b < HIST_MAX; ++b) {
            cum += hist[b];
            if (cum >= KNEIGH) { cutbin = b; break; }
        }
        int thr = cutbin + MARGIN;
        thr_s = thr > 255 ? 255 : thr;
    }
    __syncthreads();
    const unsigned thr = (unsigned)thr_s;

    // pass 2: gather candidate indices (bin <= thr)
    for (int i = t; i < NCENT / 4; i += 256) {
        uint32_t v = qp[i];
#pragma unroll
        for (int sub = 0; sub < 4; ++sub) {
            unsigned b = (v >> (8 * sub)) & 255u;
            if (b <= thr) {
                int pos = atomicAdd(&ncand, 1);
                if (pos < CAND_CAP) candIdx[pos] = 4 * i + sub;
            }
        }
    }
    __syncthreads();
    const int nc = ncand < CAND_CAP ? ncand : CAND_CAP;
    const float fnr = fnrep[row];
    const float* fp = feat + (size_t)row * DIM;

    // exact np-fp32 key (round-3-verified replication) + fp64 distance for weight
    for (int ci = t; ci < nc; ci += 256) {
        const int idx = candIdx[ci];
        const float* cp = cent + (size_t)idx * DIM;
        float acc = 0.f;
#pragma unroll
        for (int k = 0; k < DIM; ++k) acc = fmaf(2.0f * fp[k], cp[k], acc);
        float cnrep = np_sum128_sq(cp);
        {
#pragma clang fp contract(off)
            candKey[ci] = (fnr - acc) + cnrep;
        }
        double dd = 0.0;
        for (int k = 0; k < DIM; ++k) {
            double d1 = (double)fp[k] - (double)cp[k];
            dd += d1 * d1;
        }
        candW[ci] = (float)dd;
    }
    __syncthreads();

    // exact top-200 among candidates by (key, idx); accumulate class weights
    for (int ci = t; ci < nc; ci += 256) {
        const float ki = candKey[ci];
        const int ii = candIdx[ci];
        int rank = 0;
        for (int j = 0; j < nc; ++j) {
            if (j == ci) continue;
            float kj = candKey[j];
            if (kj < ki || (kj == ki && candIdx[j] < ii)) rank++;
        }
        if (rank < KNEIGH) {
            float wv = expf(kw[ii] - candW[ci] * GC);
            atomicAdd(&p[labels[ii]], wv);
        }
    }
    __syncthreads();

    // normalize: p = where(p==0, 1e-10, p); p /= sum(p); out = log(p)
    if (t == 0) {
        float s = 0.f;
        for (int c = 0; c < NCLASS; ++c) {
            float v = p[c];
            v = (v == 0.f) ? 1e-10f : v;
            p[c] = v;
            s += v;
        }
        ssum = s;
    }
    __syncthreads();
    for (int c = t; c < NCLASS; c += 256)
        out[(size_t)row * NCLASS + c] = logf(p[c] / ssum);
}

static inline size_t align256(size_t x) { return (x + 255) & ~(size_t)255; }

extern "C" void kernel_launch(void* const* d_in, const int* in_sizes, int n_in,
                              void* d_out, int out_size, void* d_ws, size_t ws_size,
                              hipStream_t stream) {
    const float* feat   = (const float*)d_in[0];  // [1024,128]
    const float* cent   = (const float*)d_in[1];  // [100000,128]
    const float* kw     = (const float*)d_in[2];  // [100000]
    const int*   labels = (const int*)d_in[3];    // [100000]
    float* out = (float*)d_out;                   // [1024,100]

    char* base = (char*)d_ws;
    size_t o = 0;
    unsigned short* centb = (unsigned short*)(base + o); o += align256((size_t)NCENT * DIM * 2);
    unsigned short* featb = (unsigned short*)(base + o); o += align256((size_t)BATCH * DIM * 2);
    float* cnorm = (float*)(base + o);                   o += align256((size_t)NCENT * 4);
    float* fnrep = (float*)(base + o);                   o += align256((size_t)BATCH * 4);
    unsigned char* qmat = (unsigned char*)(base + o);    o += align256((size_t)BATCH * NCENT);
    (void)ws_size; (void)in_sizes; (void)n_in; (void)out_size;

    prep_cent_kernel<<<NCENT / 32, 256, 0, stream>>>(cent, centb, cnorm);
    prep_feat_kernel<<<(BATCH + 255) / 256, 256, 0, stream>>>(feat, featb, fnrep);

    dim3 gg((NCENT + 511) / 512, BATCH / 128);   // 196 x 8
    mfma_coarse_kernel<<<gg, 256, 0, stream>>>(featb, centb, cnorm, qmat);

    select_kernel<<<BATCH, 256, 0, stream>>>(qmat, feat, cent, fnrep, kw, labels, out);
}